// Round 3
// baseline (97.914 us; speedup 1.0000x reference)
//
#include <hip/hip_runtime.h>
#include <math.h>
#include <float.h>
#include <stdint.h>

#define BIGINT_F 1e10f
#define L_TOK 128
#define C_ATOM 14
#define E_DIM 256
#define K_NB 9

// strict f32: ((x*x + y*y) + z*z), no FMA contraction (match np order)
__device__ __forceinline__ float sq3(float x, float y, float z) {
    return __fadd_rn(__fadd_rn(__fmul_rn(x, x), __fmul_rn(y, y)), __fmul_rn(z, z));
}

__device__ __forceinline__ uint64_t umin64(uint64_t a, uint64_t b) { return a < b ? a : b; }

// One fused kernel. Block roles by blockIdx.x:
//   [0, NKNN)      : knn+adj — 4 waves/block, one wave per row (b,i); batch staged in LDS
//   [NKNN, NKNN+N) : embed — one block per token n
__global__ void __launch_bounds__(256)
fused_kernel(const int* __restrict__ S, const int* __restrict__ RP,
             const int* __restrict__ A, const int* __restrict__ AP,
             const float* __restrict__ X, const int* __restrict__ seg,
             const float* __restrict__ res_embed,
             const float* __restrict__ atom_embed,
             const float* __restrict__ atom_pos_embed,
             float* __restrict__ h,
             float* __restrict__ ctx_src, float* __restrict__ ctx_dst, float* __restrict__ ctx_val,
             float* __restrict__ adj_out,
             float* __restrict__ int_src, float* __restrict__ int_dst, float* __restrict__ int_val,
             int N) {
    const int NKNN = N / 4;          // 4 rows per block (one per wave), all in same batch
    int blk = blockIdx.x;
    int tid = threadIdx.x;

    if (blk < NKNN) {
        // ----------------- KNN + ADJ -----------------
        int wave = tid >> 6;
        int lane = tid & 63;
        int bi = blk * 4 + wave;             // b*L + i
        int b  = bi >> 7;
        int i  = bi & (L_TOK - 1);
        int base_tok = (b << 7);

        // SoA LDS, XOR-swizzled: word(c,tok) = c*128 + (tok ^ 2c).
        // Writes (tok-major cooperative) and reads (tok=lane) both conflict-free.
        __shared__ float sX[C_ATOM * L_TOK];
        __shared__ float sY[C_ATOM * L_TOK];
        __shared__ float sZ[C_ATOM * L_TOK];
        __shared__ float sQ[C_ATOM * L_TOK];

        const float* Xb  = X  + (size_t)base_tok * C_ATOM * 3;
        const int*   APb = AP + base_tok * C_ATOM;
        for (int idx = tid; idx < L_TOK * C_ATOM; idx += 256) {
            int tok = idx / C_ATOM;
            int c   = idx - tok * C_ATOM;    // idx = tok*14 + c -> coalesced global reads
            float x0 = Xb[idx * 3 + 0];
            float x1 = Xb[idx * 3 + 1];
            float x2 = Xb[idx * 3 + 2];
            float q  = (APb[idx] == 0) ? INFINITY : sq3(x0, x1, x2);
            int w = c * L_TOK + (tok ^ (2 * c));
            sX[w] = x0; sY[w] = x1; sZ[w] = x2; sQ[w] = q;
        }
        __syncthreads();   // block-uniform path: safe

        // i-atom fragments: lane-uniform (broadcast) LDS reads
        float xa0[C_ATOM], xa1[C_ATOM], xa2[C_ATOM], sa[C_ATOM];
        #pragma unroll
        for (int a = 0; a < C_ATOM; ++a) {
            int w = a * L_TOK + (i ^ (2 * a));
            xa0[a] = sX[w]; xa1[a] = sY[w]; xa2[a] = sZ[w]; sa[a] = sQ[w];
        }

        int j0 = lane, j1 = lane + 64;
        int nj0 = base_tok + j0, nj1 = base_tok + j1;

        float mind0 = INFINITY, mind1 = INFINITY;
        for (int c = 0; c < C_ATOM; ++c) {
            int w = c * L_TOK + (lane ^ (2 * c));   // j1 word = w + 64 (bit6 untouched by 2c<32)
            float y00 = sX[w],      y01 = sY[w],      y02 = sZ[w],      sc0 = sQ[w];
            float y10 = sX[w + 64], y11 = sY[w + 64], y12 = sZ[w + 64], sc1 = sQ[w + 64];
            #pragma unroll
            for (int a = 0; a < C_ATOM; ++a) {
                float dot0 = __fadd_rn(__fadd_rn(__fmul_rn(xa0[a], y00),
                                                 __fmul_rn(xa1[a], y01)),
                                       __fmul_rn(xa2[a], y02));
                float d20 = __fsub_rn(__fadd_rn(sa[a], sc0), __fmul_rn(2.0f, dot0));
                mind0 = fminf(mind0, d20);
                float dot1 = __fadd_rn(__fadd_rn(__fmul_rn(xa0[a], y10),
                                                 __fmul_rn(xa1[a], y11)),
                                       __fmul_rn(xa2[a], y12));
                float d21 = __fsub_rn(__fadd_rn(sa[a], sc1), __fmul_rn(2.0f, dot1));
                mind1 = fminf(mind1, d21);
            }
        }
        float d0 = sqrtf(fmaxf(mind0, 0.0f));
        float d1 = sqrtf(fmaxf(mind1, 0.0f));

        int si = S[bi];
        int segi = seg[bi];
        bool gi = si >= 21;
        int sj0 = S[nj0], sj1 = S[nj1];
        int segj0 = seg[nj0], segj1 = seg[nj1];
        bool gj0 = sj0 >= 21, gj1 = sj1 >= 21;
        bool ns0 = (j0 != i), ns1 = (j1 != i);
        bool ng0 = !gi && !gj0 && ns0;
        bool ng1 = !gi && !gj1 && ns1;
        bool inner0 = (segi == segj0) && ng0;
        bool inner1 = (segi == segj1) && ng1;
        bool outer0 = (segi != segj0) && ng0;
        bool outer1 = (segi != segj1) && ng1;

        // ---- adj folded in (two coalesced 64-lane stores per wave) ----
        {
            bool gij0 = gi || gj0, gij1 = gi || gj1;
            bool same0 = (segi == segj0), same1 = (segi == segj1);
            int dd0 = i - j0, dd1 = i - j1;
            bool a0 = (dd0 == 1 || dd0 == -1), a1 = (dd1 == 1 || dd1 == -1);
            bool v0 = (same0 && gij0 && ns0) || (gi && gj0 && ns0) || (a0 && !gij0 && (segi != 1));
            bool v1 = (same1 && gij1 && ns1) || (gi && gj1 && ns1) || (a1 && !gij1 && (segi != 1));
            adj_out[(size_t)bi * L_TOK + j0] = v0 ? 1.0f : 0.0f;
            adj_out[(size_t)bi * L_TOK + j1] = v1 ? 1.0f : 0.0f;
        }

        const uint32_t bigbits = __float_as_uint(BIGINT_F);
        uint64_t kd0 = ((uint64_t)__float_as_uint(d0) << 32) | (uint32_t)j0;
        uint64_t kd1 = ((uint64_t)__float_as_uint(d1) << 32) | (uint32_t)j1;
        uint64_t kbig0 = ((uint64_t)bigbits << 32) | (uint32_t)j0;
        uint64_t kbig1 = ((uint64_t)bigbits << 32) | (uint32_t)j1;

        for (int pass = 0; pass < 2; ++pass) {
            uint64_t k0 = (pass == 0 ? inner0 : outer0) ? kd0 : kbig0;
            uint64_t k1 = (pass == 0 ? inner1 : outer1) ? kd1 : kbig1;
            float* osrc = (pass == 0) ? ctx_src : int_src;
            float* odst = (pass == 0) ? ctx_dst : int_dst;
            float* oval = (pass == 0) ? ctx_val : int_val;
            #pragma unroll
            for (int k = 0; k < K_NB; ++k) {
                uint64_t kk = umin64(k0, k1);
                #pragma unroll
                for (int m = 32; m > 0; m >>= 1) {
                    uint64_t o = __shfl_xor((unsigned long long)kk, m, 64);
                    kk = umin64(kk, o);
                }
                if (k0 == kk) k0 = UINT64_MAX;
                if (k1 == kk) k1 = UINT64_MAX;
                if (lane == 0) {
                    uint32_t dbits = (uint32_t)(kk >> 32);
                    int jmin = (int)(uint32_t)kk;
                    bool valid = dbits < bigbits;   // d < BIGINT strictly
                    int o = bi * K_NB + k;
                    osrc[o] = valid ? (float)bi : -1.0f;
                    odst[o] = valid ? (float)(base_tok + jmin) : -1.0f;
                    oval[o] = valid ? 1.0f : 0.0f;
                }
            }
        }
    } else {
        // ----------------- EMBED: one block per token -----------------
        int n = blk - NKNN;
        int e = tid;  // 0..255
        int s = S[n];
        float rp = (float)RP[n];

        int k = e >> 1;
        // 10000^(-2k/E) = exp2(k * (-2*log2(10000)/E))
        const float c1 = (float)(-2.0 * 13.287712379549449 / (double)E_DIM);
        float invk = exp2f((float)k * c1);
        float ang = rp * invk;
        float pe = (e & 1) ? cosf(ang) : sinf(ang);
        h[(size_t)n * (2 * E_DIM) + e] = res_embed[s * E_DIM + e] + pe;

        __shared__ int sA[C_ATOM], sAP[C_ATOM];
        if (e < C_ATOM) { sA[e] = A[n * C_ATOM + e]; sAP[e] = AP[n * C_ATOM + e]; }
        __syncthreads();

        float sum = 0.0f, cnt = 0.0f;
        for (int c = 0; c < C_ATOM; ++c) {
            if (sAP[c] != 0) {   // block-uniform branch: no divergence
                sum += atom_embed[sA[c] * E_DIM + e] + atom_pos_embed[sAP[c] * E_DIM + e];
                cnt += 1.0f;
            }
        }
        h[(size_t)n * (2 * E_DIM) + E_DIM + e] = sum / (cnt + 1e-10f);
    }
}

extern "C" void kernel_launch(void* const* d_in, const int* in_sizes, int n_in,
                              void* d_out, int out_size, void* d_ws, size_t ws_size,
                              hipStream_t stream) {
    const int*   S    = (const int*)d_in[0];
    const int*   RP   = (const int*)d_in[1];
    const int*   A    = (const int*)d_in[2];
    const int*   AP   = (const int*)d_in[3];
    const float* X    = (const float*)d_in[4];
    const int*   seg  = (const int*)d_in[5];
    const float* rese = (const float*)d_in[6];
    const float* atme = (const float*)d_in[7];
    const float* atpe = (const float*)d_in[8];

    const int N = in_sizes[0];       // 2048
    const int B = N / L_TOK;         // 16
    float* out = (float*)d_out;

    size_t off = 0;
    float* h_out   = out + off;  off += (size_t)N * 2 * E_DIM;
    float* ctx_src = out + off;  off += (size_t)N * K_NB;
    float* ctx_dst = out + off;  off += (size_t)N * K_NB;
    float* ctx_val = out + off;  off += (size_t)N * K_NB;
    float* adj_out = out + off;  off += (size_t)B * L_TOK * L_TOK;
    float* int_src = out + off;  off += (size_t)N * K_NB;
    float* int_dst = out + off;  off += (size_t)N * K_NB;
    float* int_val = out + off;  off += (size_t)N * K_NB;

    int nknn = N / 4;                 // 512
    int grid = nknn + N;              // 2560
    fused_kernel<<<grid, 256, 0, stream>>>(S, RP, A, AP, X, seg, rese, atme, atpe,
                                           h_out, ctx_src, ctx_dst, ctx_val,
                                           adj_out, int_src, int_dst, int_val, N);
}